// Round 2
// baseline (534.183 us; speedup 1.0000x reference)
//
#include <hip/hip_runtime.h>
#include <hip/hip_bf16.h>
#include <cstdint>
#include <cstddef>

// Problem constants (Attention_17042430230543)
#define BATCH 4
#define TSEQ  2048
#define CDIM  1024
#define NH    16
#define HDIM  64
#define MTOT  (BATCH * TSEQ)   // 8192

typedef __attribute__((ext_vector_type(4))) float  floatx4;
typedef __attribute__((ext_vector_type(8))) short  shortx8;
typedef __attribute__((ext_vector_type(4))) short  shortx4;

__device__ __forceinline__ float bf2f(short s) {
    union { unsigned int u; float f; } v;
    v.u = ((unsigned int)(unsigned short)s) << 16;
    return v.f;
}
__device__ __forceinline__ short f2bf(float f) {
    union { float f; unsigned int u; } v; v.f = f;
    unsigned int lsb = (v.u >> 16) & 1u;
    v.u += 0x7fffu + lsb;           // round-to-nearest-even
    return (short)(v.u >> 16);
}

// -------------------------------------------------------------------------
// Dtype detection: for bf16-packed data, bits[14:7] of each 32b word are the
// low-half bf16's exponent (concentrated near 127 for N(0,1) data). For fp32
// data they're uniform mantissa tail bits (~4.7% in-range). flag=1 -> bf16.
// -------------------------------------------------------------------------
__global__ __launch_bounds__(256) void detect_kernel(const unsigned int* __restrict__ w,
                                                     int* __restrict__ flag)
{
    int tid = threadIdx.x;
    int cnt = 0;
#pragma unroll
    for (int i = 0; i < 4; ++i) {
        unsigned int x = w[tid * 4 + i];
        unsigned int e = (x >> 7) & 0xFF;
        cnt += (e >= 118 && e <= 129) ? 1 : 0;
    }
    __shared__ int sh[4];
#pragma unroll
    for (int off = 1; off < 64; off <<= 1) cnt += __shfl_xor(cnt, off);
    if ((tid & 63) == 0) sh[tid >> 6] = cnt;
    __syncthreads();
    if (tid == 0) {
        int t = sh[0] + sh[1] + sh[2] + sh[3];
        *flag = (t > 512) ? 1 : 0;
    }
}

template<bool BF16>
__device__ __forceinline__ float load_scalar(const void* p, int idx) {
    if constexpr (BF16) return bf2f(((const short*)p)[idx]);
    else                return ((const float*)p)[idx];
}

// Stage a 128x32 tile (rows row0..row0+127, cols k0..k0+31 of a [*,K] matrix)
// into bf16 LDS tile S[128][32]. BF16 path: global_load_lds width 16 (m97).
// FP32 path: float4 load + convert + ds_write.
template<bool BF16>
__device__ __forceinline__ void stage128x32(const void* G, short* S, int row0,
                                            int K, int k0, int tid, int wave)
{
    if constexpr (BF16) {
        const short* g = (const short*)G;
#pragma unroll
        for (int i = 0; i < 2; ++i) {
            int c = i * 256 + tid;            // 16B chunk index
            int r = c >> 2, kc = c & 3;
            __builtin_amdgcn_global_load_lds(
                (__attribute__((address_space(1))) void*)(g + (size_t)(row0 + r) * K + k0 + kc * 8),
                (__attribute__((address_space(3))) void*)((char*)S + i * 4096 + wave * 1024),
                16, 0, 0);
        }
    } else {
        const float* g = (const float*)G;
#pragma unroll
        for (int i = 0; i < 4; ++i) {
            int c = i * 256 + tid;            // 4-float chunk index
            int r = c >> 3, fc = c & 7;
            const float4 v = *(const float4*)(g + (size_t)(row0 + r) * K + k0 + fc * 4);
            shortx4 s4;
            s4[0] = f2bf(v.x); s4[1] = f2bf(v.y); s4[2] = f2bf(v.z); s4[3] = f2bf(v.w);
            *(shortx4*)(S + r * 32 + fc * 4) = s4;
        }
    }
}

// -------------------------------------------------------------------------
// GEMM1: qkv = hs @ W_qkv^T + b_qkv ; scatter into Q,K,V [B,H,T,D] bf16.
// 128x128 tile, BK=32, 4 waves, each wave 64x64 as 4x4 MFMA 16x16x32.
// -------------------------------------------------------------------------
template<bool BF16>
__device__ void gemm_qkv_body(const void* __restrict__ A, const void* __restrict__ W,
                              const void* __restrict__ bias,
                              short* __restrict__ Qo, short* __restrict__ Ko,
                              short* __restrict__ Vo, short* As, short* Bs)
{
    const int tid  = threadIdx.x;
    const int lane = tid & 63, wave = tid >> 6;
    const int quad = lane >> 4, l16 = lane & 15;
    const int wr = wave >> 1, wc = wave & 1;
    const int row0 = blockIdx.x * 128;
    const int col0 = blockIdx.y * 128;
    const int K = CDIM;

    floatx4 acc[4][4] = {};

    for (int k0 = 0; k0 < K; k0 += 32) {
        stage128x32<BF16>(A, As, row0, K, k0, tid, wave);
        stage128x32<BF16>(W, Bs, col0, K, k0, tid, wave);
        __syncthreads();

        shortx8 af[4], bfr[4];
#pragma unroll
        for (int mi = 0; mi < 4; ++mi)
            af[mi] = *(const shortx8*)(As + (wr * 64 + mi * 16 + l16) * 32 + quad * 8);
#pragma unroll
        for (int ni = 0; ni < 4; ++ni)
            bfr[ni] = *(const shortx8*)(Bs + (wc * 64 + ni * 16 + l16) * 32 + quad * 8);
#pragma unroll
        for (int mi = 0; mi < 4; ++mi)
#pragma unroll
            for (int ni = 0; ni < 4; ++ni)
                acc[mi][ni] = __builtin_amdgcn_mfma_f32_16x16x32_bf16(
                    af[mi], bfr[ni], acc[mi][ni], 0, 0, 0);
        __syncthreads();
    }

    // Epilogue: scatter to Q/K/V [B,H,T,D] bf16, fold 1/sqrt(D)=0.125 into Q.
#pragma unroll
    for (int mi = 0; mi < 4; ++mi) {
        int m = row0 + wr * 64 + mi * 16 + quad * 4;
#pragma unroll
        for (int ni = 0; ni < 4; ++ni) {
            int n = col0 + wc * 64 + ni * 16 + l16;
            float bv = load_scalar<BF16>(bias, n);
            int part = n >> 10, rem = n & 1023;
            int h = rem >> 6, d = rem & 63;
            short* dst = (part == 0) ? Qo : (part == 1 ? Ko : Vo);
            float scale = (part == 0) ? 0.125f : 1.0f;
#pragma unroll
            for (int r = 0; r < 4; ++r) {
                int mm = m + r;
                int b = mm >> 11, t = mm & (TSEQ - 1);
                size_t idx = (((size_t)(b * NH + h)) * TSEQ + t) * HDIM + d;
                dst[idx] = f2bf((acc[mi][ni][r] + bv) * scale);
            }
        }
    }
}

__global__ __launch_bounds__(256) void gemm_qkv_kernel(
    const void* __restrict__ A, const void* __restrict__ W, const void* __restrict__ bias,
    short* __restrict__ Qo, short* __restrict__ Ko, short* __restrict__ Vo,
    const int* __restrict__ flag)
{
    __shared__ short As[128 * 32];
    __shared__ short Bs[128 * 32];
    if (*flag) gemm_qkv_body<true >(A, W, bias, Qo, Ko, Vo, As, Bs);
    else       gemm_qkv_body<false>(A, W, bias, Qo, Ko, Vo, As, Bs);
}

// -------------------------------------------------------------------------
// Flash attention (causal). One block = 128 Q rows of one (b,h). All-bf16
// workspace I/O -> dtype-independent. 4 waves; wave w owns Q rows
// [w*32,w*32+32) so online softmax is wave-local. K staged via
// global_load_lds with XOR chunk swizzle; V transposed in LDS; P round-trips
// per-wave LDS (C/D layout -> A-operand layout).
// -------------------------------------------------------------------------
__global__ __launch_bounds__(256) void attn_kernel(
    const short* __restrict__ Q,   // [B*H, T, D] bf16, pre-scaled by 0.125
    const short* __restrict__ Km,  // [B*H, T, D]
    const short* __restrict__ V,   // [B*H, T, D]
    const int*   __restrict__ am,  // [B, T]
    short* __restrict__ O)         // [B, T, C] bf16
{
    __shared__ short Ks[64 * 64];        // swizzled chunk layout, 8KB
    __shared__ short Vt[64 * 72];        // transposed [d][kv], padded, 9KB
    __shared__ short Ps[4][32 * 72];     // per-wave P, padded, 18KB

    const int tid  = threadIdx.x;
    const int lane = tid & 63, wave = tid >> 6;
    const int quad = lane >> 4, l16 = lane & 15;
    const int q0 = blockIdx.x * 128;
    const int bh = blockIdx.y;
    const int b  = bh >> 4;
    const int h  = bh & 15;

    const short* Qb = Q  + (size_t)bh * TSEQ * HDIM;
    const short* Kb = Km + (size_t)bh * TSEQ * HDIM;
    const short* Vb = V  + (size_t)bh * TSEQ * HDIM;

    shortx8 aq[2][2];
#pragma unroll
    for (int mi = 0; mi < 2; ++mi)
#pragma unroll
        for (int kk = 0; kk < 2; ++kk)
            aq[mi][kk] = *(const shortx8*)(
                Qb + (size_t)(q0 + wave * 32 + mi * 16 + l16) * HDIM + kk * 32 + quad * 8);

    floatx4 o[2][4] = {};
    float mst[2][4], lst[2][4];
#pragma unroll
    for (int mi = 0; mi < 2; ++mi)
#pragma unroll
        for (int r = 0; r < 4; ++r) { mst[mi][r] = -INFINITY; lst[mi][r] = 0.f; }

    const int kvend = q0 + 128;
    for (int kt0 = 0; kt0 < kvend; kt0 += 64) {
        // ---- stage K (async, swizzled) and V (register transpose) ----
#pragma unroll
        for (int i = 0; i < 2; ++i) {
            int c = i * 256 + tid;
            int rr = c >> 3;
            int dcs = (c & 7) ^ (rr & 7);   // swizzled source chunk
            const short* gK = Kb + (size_t)(kt0 + rr) * HDIM + dcs * 8;
            __builtin_amdgcn_global_load_lds(
                (__attribute__((address_space(1))) void*)gK,
                (__attribute__((address_space(3))) void*)((char*)Ks + i * 4096 + wave * 1024),
                16, 0, 0);
            int dc2 = c & 7;
            shortx8 v8 = *(const shortx8*)(Vb + (size_t)(kt0 + rr) * HDIM + dc2 * 8);
#pragma unroll
            for (int j = 0; j < 8; ++j)
                Vt[(dc2 * 8 + j) * 72 + rr] = v8[j];
        }
        __syncthreads();

        // ---- S = Q K^T (per wave: 32 x 64) ----
        floatx4 s[2][4] = {};
#pragma unroll
        for (int kk = 0; kk < 2; ++kk) {
#pragma unroll
            for (int ni = 0; ni < 4; ++ni) {
                int rrow = ni * 16 + l16;                 // kv index in tile
                int dcr = (kk * 4 + quad) ^ (rrow & 7);   // swizzled chunk
                shortx8 bk = *(const shortx8*)(Ks + (rrow * 8 + dcr) * 8);
#pragma unroll
                for (int mi = 0; mi < 2; ++mi)
                    s[mi][ni] = __builtin_amdgcn_mfma_f32_16x16x32_bf16(
                        aq[mi][kk], bk, s[mi][ni], 0, 0, 0);
            }
        }

        // ---- causal + key mask ----
        int kvc[4]; int amv[4];
#pragma unroll
        for (int ni = 0; ni < 4; ++ni) {
            kvc[ni] = kt0 + ni * 16 + l16;
            amv[ni] = am[b * TSEQ + kvc[ni]];
        }
#pragma unroll
        for (int mi = 0; mi < 2; ++mi) {
            int qr = q0 + wave * 32 + mi * 16 + quad * 4;
#pragma unroll
            for (int ni = 0; ni < 4; ++ni)
#pragma unroll
                for (int r = 0; r < 4; ++r)
                    if (kvc[ni] > qr + r || amv[ni] == 0) s[mi][ni][r] = -INFINITY;
        }

        // ---- online softmax (wave-local; 16 lanes share a row) ----
#pragma unroll
        for (int mi = 0; mi < 2; ++mi) {
#pragma unroll
            for (int r = 0; r < 4; ++r) {
                float mx = fmaxf(fmaxf(s[mi][0][r], s[mi][1][r]),
                                 fmaxf(s[mi][2][r], s[mi][3][r]));
                mx = fmaxf(mx, __shfl_xor(mx, 1));
                mx = fmaxf(mx, __shfl_xor(mx, 2));
                mx = fmaxf(mx, __shfl_xor(mx, 4));
                mx = fmaxf(mx, __shfl_xor(mx, 8));
                float mnew  = fmaxf(mst[mi][r], mx);
                float alpha = __expf(mst[mi][r] - mnew);
                float rs = 0.f;
#pragma unroll
                for (int ni = 0; ni < 4; ++ni) {
                    float p = __expf(s[mi][ni][r] - mnew);
                    s[mi][ni][r] = p;
                    rs += p;
                }
                rs += __shfl_xor(rs, 1);
                rs += __shfl_xor(rs, 2);
                rs += __shfl_xor(rs, 4);
                rs += __shfl_xor(rs, 8);
                lst[mi][r] = lst[mi][r] * alpha + rs;
                mst[mi][r] = mnew;
#pragma unroll
                for (int ndi = 0; ndi < 4; ++ndi) o[mi][ndi][r] *= alpha;
            }
        }

        // ---- P: C/D layout -> LDS -> A-operand layout ----
        short* Pw = Ps[wave];
#pragma unroll
        for (int mi = 0; mi < 2; ++mi)
#pragma unroll
            for (int ni = 0; ni < 4; ++ni)
#pragma unroll
                for (int r = 0; r < 4; ++r)
                    Pw[(mi * 16 + quad * 4 + r) * 72 + ni * 16 + l16] = f2bf(s[mi][ni][r]);
        __syncthreads();

        // ---- O += P V ----
#pragma unroll
        for (int kk = 0; kk < 2; ++kk) {
            shortx8 ap[2];
#pragma unroll
            for (int mi = 0; mi < 2; ++mi)
                ap[mi] = *(const shortx8*)(Pw + (mi * 16 + l16) * 72 + kk * 32 + quad * 8);
#pragma unroll
            for (int ndi = 0; ndi < 4; ++ndi) {
                shortx8 bv = *(const shortx8*)(Vt + (ndi * 16 + l16) * 72 + kk * 32 + quad * 8);
#pragma unroll
                for (int mi = 0; mi < 2; ++mi)
                    o[mi][ndi] = __builtin_amdgcn_mfma_f32_16x16x32_bf16(
                        ap[mi], bv, o[mi][ndi], 0, 0, 0);
            }
        }
        __syncthreads();
    }

    // ---- epilogue: O /= l, write [B,T,H,D] bf16 workspace ----
#pragma unroll
    for (int mi = 0; mi < 2; ++mi) {
#pragma unroll
        for (int r = 0; r < 4; ++r) {
            int t = q0 + wave * 32 + quad * 4 + mi * 16 + r;
            float inv = 1.0f / lst[mi][r];
#pragma unroll
            for (int ndi = 0; ndi < 4; ++ndi) {
                int d = ndi * 16 + l16;
                O[((size_t)b * TSEQ + t) * CDIM + h * HDIM + d] = f2bf(o[mi][ndi][r] * inv);
            }
        }
    }
}

// -------------------------------------------------------------------------
// GEMM2: out = attn @ W_o^T + b_o  ([8192,1024] x [1024,1024]^T)
// A (attn out) is always bf16 workspace; W/bias/Out follow the input dtype.
// -------------------------------------------------------------------------
template<bool BF16>
__device__ void gemm_out_body(const short* __restrict__ A, const void* __restrict__ W,
                              const void* __restrict__ bias, void* __restrict__ Out,
                              short* As, short* Bs)
{
    const int tid  = threadIdx.x;
    const int lane = tid & 63, wave = tid >> 6;
    const int quad = lane >> 4, l16 = lane & 15;
    const int wr = wave >> 1, wc = wave & 1;
    const int row0 = blockIdx.x * 128;
    const int col0 = blockIdx.y * 128;
    const int K = CDIM;

    floatx4 acc[4][4] = {};

    for (int k0 = 0; k0 < K; k0 += 32) {
        stage128x32<true>(A, As, row0, K, k0, tid, wave);   // ws always bf16
        stage128x32<BF16>(W, Bs, col0, K, k0, tid, wave);
        __syncthreads();

        shortx8 af[4], bfr[4];
#pragma unroll
        for (int mi = 0; mi < 4; ++mi)
            af[mi] = *(const shortx8*)(As + (wr * 64 + mi * 16 + l16) * 32 + quad * 8);
#pragma unroll
        for (int ni = 0; ni < 4; ++ni)
            bfr[ni] = *(const shortx8*)(Bs + (wc * 64 + ni * 16 + l16) * 32 + quad * 8);
#pragma unroll
        for (int mi = 0; mi < 4; ++mi)
#pragma unroll
            for (int ni = 0; ni < 4; ++ni)
                acc[mi][ni] = __builtin_amdgcn_mfma_f32_16x16x32_bf16(
                    af[mi], bfr[ni], acc[mi][ni], 0, 0, 0);
        __syncthreads();
    }

#pragma unroll
    for (int mi = 0; mi < 4; ++mi) {
        int m = row0 + wr * 64 + mi * 16 + quad * 4;
#pragma unroll
        for (int ni = 0; ni < 4; ++ni) {
            int n = col0 + wc * 64 + ni * 16 + l16;
            float bv = load_scalar<BF16>(bias, n);
#pragma unroll
            for (int r = 0; r < 4; ++r) {
                float val = acc[mi][ni][r] + bv;
                if constexpr (BF16) ((short*)Out)[(size_t)(m + r) * CDIM + n] = f2bf(val);
                else                ((float*)Out)[(size_t)(m + r) * CDIM + n] = val;
            }
        }
    }
}

__global__ __launch_bounds__(256) void gemm_out_kernel(
    const short* __restrict__ A, const void* __restrict__ W, const void* __restrict__ bias,
    void* __restrict__ Out, const int* __restrict__ flag)
{
    __shared__ short As[128 * 32];
    __shared__ short Bs[128 * 32];
    if (*flag) gemm_out_body<true >(A, W, bias, Out, As, Bs);
    else       gemm_out_body<false>(A, W, bias, Out, As, Bs);
}

// -------------------------------------------------------------------------
// Workspace: [flag int @0, pad to 256B] | Q 16MB | K 16MB | V 16MB | Aw 16MB
// -------------------------------------------------------------------------
extern "C" void kernel_launch(void* const* d_in, const int* in_sizes, int n_in,
                              void* d_out, int out_size, void* d_ws, size_t ws_size,
                              hipStream_t stream)
{
    const void* hs   = d_in[0];                 // hidden_states [4,2048,1024]
    const int*  am   = (const int*)d_in[1];     // attn_mask int32 [4,2048]
    const void* Wqkv = d_in[2];                 // [3072,1024]
    const void* bqkv = d_in[3];                 // [3072]
    const void* Wo   = d_in[4];                 // [1024,1024]
    const void* bo   = d_in[5];                 // [1024]

    char* ws = (char*)d_ws;
    int*   flag = (int*)ws;
    short* Qw = (short*)(ws + 256);
    short* Kw = (short*)(ws + 256 + (size_t)16 * 1024 * 1024);
    short* Vw = (short*)(ws + 256 + (size_t)32 * 1024 * 1024);
    short* Aw = (short*)(ws + 256 + (size_t)48 * 1024 * 1024);

    detect_kernel<<<1, 256, 0, stream>>>((const unsigned int*)hs, flag);
    gemm_qkv_kernel<<<dim3(MTOT / 128, (3 * CDIM) / 128), 256, 0, stream>>>(
        hs, Wqkv, bqkv, Qw, Kw, Vw, flag);
    attn_kernel<<<dim3(TSEQ / 128, BATCH * NH), 256, 0, stream>>>(
        Qw, Kw, Vw, am, Aw);
    gemm_out_kernel<<<dim3(MTOT / 128, CDIM / 128), 256, 0, stream>>>(
        Aw, Wo, bo, (void*)d_out, flag);
}

// Round 3
// 337.718 us; speedup vs baseline: 1.5817x; 1.5817x over previous
//
#include <hip/hip_runtime.h>
#include <cstdint>
#include <cstddef>
#include <math.h>

// Problem constants (Attention_17042430230543): fp32 in / fp32 out (proven R2)
#define BATCH 4
#define TSEQ  2048
#define CDIM  1024
#define NH    16
#define HDIM  64
#define MTOT  (BATCH * TSEQ)   // 8192

typedef __attribute__((ext_vector_type(4))) float  floatx4;
typedef __attribute__((ext_vector_type(8))) short  shortx8;
typedef __attribute__((ext_vector_type(4))) short  shortx4;

__device__ __forceinline__ short f2bf(float f) {
    union { float f; unsigned int u; } v; v.f = f;
    unsigned int lsb = (v.u >> 16) & 1u;
    v.u += 0x7fffu + lsb;           // RNE
    return (short)(v.u >> 16);
}

#if defined(__has_builtin)
#  if __has_builtin(__builtin_amdgcn_exp2f)
#    define EXP2F(x) __builtin_amdgcn_exp2f(x)
#  else
#    define EXP2F(x) exp2f(x)
#  endif
#  if __has_builtin(__builtin_amdgcn_perm)
__device__ __forceinline__ unsigned pack_hi16(unsigned hi, unsigned lo) {
    return __builtin_amdgcn_perm(hi, lo, 0x07060302u);   // [lo>>16, hi>>16]
}
#  else
__device__ __forceinline__ unsigned pack_hi16(unsigned hi, unsigned lo) {
    return (lo >> 16) | (hi & 0xffff0000u);
}
#  endif
#  if __has_builtin(__builtin_amdgcn_mfma_f32_16x16x16bf16_1k)
#    define HAS_MFMA_1K 1
#  else
#    define HAS_MFMA_1K 0
#  endif
#else
#  define EXP2F(x) exp2f(x)
__device__ __forceinline__ unsigned pack_hi16(unsigned hi, unsigned lo) {
    return (lo >> 16) | (hi & 0xffff0000u);
}
#  define HAS_MFMA_1K 0
#endif

// log2(e) folded into Q so softmax exp runs on raw v_exp_f32 (exp2).
#define QSCALE (0.125f * 1.44269504088896f)

// -------------------------------------------------------------------------
// fp32 -> bf16 elementwise convert (memory-bound)
// -------------------------------------------------------------------------
__global__ __launch_bounds__(256) void cvt_kernel(const float4* __restrict__ src,
                                                  shortx4* __restrict__ dst, int n4)
{
    int i = blockIdx.x * 256 + threadIdx.x;
    if (i < n4) {
        float4 v = src[i];
        shortx4 s;
        s[0] = f2bf(v.x); s[1] = f2bf(v.y); s[2] = f2bf(v.z); s[3] = f2bf(v.w);
        dst[i] = s;
    }
}

// Stage 128x32 bf16 tile via async global_load_lds (width 16).
__device__ __forceinline__ void stageA_bf16(const short* g, short* S, int row0,
                                            int K, int k0, int tid, int wave)
{
#pragma unroll
    for (int i = 0; i < 2; ++i) {
        int c = i * 256 + tid;            // 16B chunk index
        int r = c >> 2, kc = c & 3;
        __builtin_amdgcn_global_load_lds(
            (__attribute__((address_space(1))) void*)(g + (size_t)(row0 + r) * K + k0 + kc * 8),
            (__attribute__((address_space(3))) void*)((char*)S + i * 4096 + wave * 1024),
            16, 0, 0);
    }
}
// Stage 128x32 from fp32 source, converting to bf16.
__device__ __forceinline__ void stageB_f32(const float* g, short* S, int row0,
                                           int K, int k0, int tid)
{
#pragma unroll
    for (int i = 0; i < 4; ++i) {
        int c = i * 256 + tid;            // 4-float chunk index
        int r = c >> 3, fc = c & 7;
        const float4 v = *(const float4*)(g + (size_t)(row0 + r) * K + k0 + fc * 4);
        shortx4 s4;
        s4[0] = f2bf(v.x); s4[1] = f2bf(v.y); s4[2] = f2bf(v.z); s4[3] = f2bf(v.w);
        *(shortx4*)(S + r * 32 + fc * 4) = s4;
    }
}

// -------------------------------------------------------------------------
// GEMM1: qkv = hsb @ Wqkv^T + b. A bf16 (pre-converted), B fp32 (cvt in-stage).
// Epilogue: Q scaled by 0.125*log2e -> [B,H,T,D]; K -> [B,H,T,D]; V -> [B,H,D,T].
// -------------------------------------------------------------------------
__global__ __launch_bounds__(256) void gemm_qkv_kernel(
    const short* __restrict__ A,      // hsb [MTOT, CDIM] bf16
    const float* __restrict__ W,      // [3C, C] fp32
    const float* __restrict__ bias,   // [3C] fp32
    short* __restrict__ Qo, short* __restrict__ Ko, short* __restrict__ VTo)
{
    __shared__ short As[128 * 32];
    __shared__ short Bs[128 * 32];
    const int tid  = threadIdx.x;
    const int lane = tid & 63, wave = tid >> 6;
    const int quad = lane >> 4, l16 = lane & 15;
    const int wr = wave >> 1, wc = wave & 1;
    const int row0 = blockIdx.x * 128;
    const int col0 = blockIdx.y * 128;
    const int K = CDIM;

    floatx4 acc[4][4] = {};

    for (int k0 = 0; k0 < K; k0 += 32) {
        stageA_bf16(A, As, row0, K, k0, tid, wave);
        stageB_f32(W, Bs, col0, K, k0, tid);
        __syncthreads();

        shortx8 af[4], bfr[4];
#pragma unroll
        for (int mi = 0; mi < 4; ++mi)
            af[mi] = *(const shortx8*)(As + (wr * 64 + mi * 16 + l16) * 32 + quad * 8);
#pragma unroll
        for (int ni = 0; ni < 4; ++ni)
            bfr[ni] = *(const shortx8*)(Bs + (wc * 64 + ni * 16 + l16) * 32 + quad * 8);
#pragma unroll
        for (int mi = 0; mi < 4; ++mi)
#pragma unroll
            for (int ni = 0; ni < 4; ++ni)
                acc[mi][ni] = __builtin_amdgcn_mfma_f32_16x16x32_bf16(
                    af[mi], bfr[ni], acc[mi][ni], 0, 0, 0);
        __syncthreads();
    }

#pragma unroll
    for (int mi = 0; mi < 4; ++mi) {
        int m = row0 + wr * 64 + mi * 16 + quad * 4;
        int b = m >> 11, t0 = m & (TSEQ - 1);
#pragma unroll
        for (int ni = 0; ni < 4; ++ni) {
            int n = col0 + wc * 64 + ni * 16 + l16;
            float bv = bias[n];
            int part = n >> 10, rem = n & 1023;
            int h = rem >> 6, d = rem & 63;
            if (part == 2) {
                // V^T [B,H,D,T]: 4 consecutive t -> vector store
                shortx4 st;
#pragma unroll
                for (int r = 0; r < 4; ++r) st[r] = f2bf(acc[mi][ni][r] + bv);
                *(shortx4*)(VTo + (((size_t)(b * NH + h)) * HDIM + d) * TSEQ + t0) = st;
            } else {
                short* dst = (part == 0) ? Qo : Ko;
                float scale = (part == 0) ? QSCALE : 1.0f;
#pragma unroll
                for (int r = 0; r < 4; ++r) {
                    size_t idx = (((size_t)(b * NH + h)) * TSEQ + (t0 + r)) * HDIM + d;
                    dst[idx] = f2bf((acc[mi][ni][r] + bv) * scale);
                }
            }
        }
    }
}

// -------------------------------------------------------------------------
// Flash attention, S^T formulation. Block = paired q-strips {s, 15-s} of one
// (b,h) -> uniform 34 kv-tiles/block. Wave owns 32 q columns.
// S^T = K·Q^T (A=K natural, B=Q natural, both direct loads). Softmax over
// C-rows (kv): 2 shuffles per q-group. P^T in C-layout == B-operand of
// mfma_16x16x16 -> PV needs no LDS round-trip. O^T accumulated [d][q].
// K and V^T staged via swizzled global_load_lds (conflict-free reads).
// -------------------------------------------------------------------------
__global__ __launch_bounds__(256) void attn_kernel(
    const short* __restrict__ Q,    // [B*H, T, D] bf16, pre-scaled
    const short* __restrict__ Kg,   // [B*H, T, D] bf16
    const short* __restrict__ VT,   // [B*H, D, T] bf16
    const int*   __restrict__ am,   // [B, T]
    short* __restrict__ O)          // [B, T, C] bf16
{
    __shared__ short Ks[64 * 64];   // swizzled [kv][d]
    __shared__ short Vs[64 * 64];   // swizzled [d][kv]

    const int tid  = threadIdx.x;
    const int lane = tid & 63, wave = tid >> 6;
    const int quad = lane >> 4, l16 = lane & 15;
    const int bh = blockIdx.y, b = bh >> 4, h = bh & 15;

    const short* Qb = Q  + (size_t)bh * TSEQ * HDIM;
    const short* Kb = Kg + (size_t)bh * TSEQ * HDIM;
    const short* Vb = VT + (size_t)bh * HDIM * TSEQ;

    for (int pass = 0; pass < 2; ++pass) {
        const int strip = pass ? (15 - blockIdx.x) : blockIdx.x;
        const int q0  = strip * 128;
        const int qb0 = q0 + wave * 32;
        const int qv0 = qb0 + l16;         // q for nq=0
        const int qv1 = qv0 + 16;          // q for nq=1

        // Q fragments (B operand): lane l16 = q, quad*8 = d-chunk
        shortx8 bq[2][2];
#pragma unroll
        for (int nq = 0; nq < 2; ++nq)
#pragma unroll
            for (int kk = 0; kk < 2; ++kk)
                bq[nq][kk] = *(const shortx8*)(
                    Qb + (size_t)(qb0 + nq * 16 + l16) * HDIM + kk * 32 + quad * 8);

        floatx4 o[4][2] = {};
        float ms[2] = { -INFINITY, -INFINITY };
        float ls[2] = { 0.f, 0.f };

        const int ntiles = (q0 + 128) >> 6;
        for (int kt = 0; kt < ntiles; ++kt) {
            const int kt0 = kt << 6;
            // ---- stage K [kv][d] and V^T [d][kv], XOR-chunk swizzled ----
#pragma unroll
            for (int i = 0; i < 2; ++i) {
                int idx = i * 256 + tid;
                int rr = idx >> 3, cd = idx & 7;
                int c = cd ^ (rr & 7);      // source chunk for swizzled dest
                __builtin_amdgcn_global_load_lds(
                    (__attribute__((address_space(1))) void*)(Kb + (size_t)(kt0 + rr) * HDIM + c * 8),
                    (__attribute__((address_space(3))) void*)((char*)Ks + i * 4096 + wave * 1024),
                    16, 0, 0);
                __builtin_amdgcn_global_load_lds(
                    (__attribute__((address_space(1))) void*)(Vb + (size_t)rr * TSEQ + kt0 + c * 8),
                    (__attribute__((address_space(3))) void*)((char*)Vs + i * 4096 + wave * 1024),
                    16, 0, 0);
            }
            int amv = am[b * TSEQ + kt0 + lane];
            bool allones = (__ballot(amv != 0) == 0xFFFFFFFFFFFFFFFFULL);
            __syncthreads();

            // ---- S^T = K Q^T : s[t][nq], row=kv=quad*4+r, col=q=l16 ----
            floatx4 s[4][2] = {};
#pragma unroll
            for (int kk = 0; kk < 2; ++kk)
#pragma unroll
                for (int t = 0; t < 4; ++t) {
                    int rr = t * 16 + l16;
                    shortx8 kf = *(const shortx8*)(
                        Ks + rr * 64 + (((kk * 4 + quad) ^ (l16 & 7)) << 3));
#pragma unroll
                    for (int nq = 0; nq < 2; ++nq)
                        s[t][nq] = __builtin_amdgcn_mfma_f32_16x16x32_bf16(
                            kf, bq[nq][kk], s[t][nq], 0, 0, 0);
                }

            // ---- online softmax + P^T pack (per q-group nq) ----
            unsigned pk[4][2][2];
#pragma unroll
            for (int nq = 0; nq < 2; ++nq) {
                const int qv = nq ? qv1 : qv0;
                float mx = s[0][nq][0];
#pragma unroll
                for (int t = 0; t < 4; ++t)
#pragma unroll
                    for (int r = 0; r < 4; ++r) mx = fmaxf(mx, s[t][nq][r]);
                mx = fmaxf(mx, __shfl_xor(mx, 16));
                mx = fmaxf(mx, __shfl_xor(mx, 32));
                float mnew  = fmaxf(ms[nq], mx);
                float alpha = EXP2F(ms[nq] - mnew);
                ms[nq] = mnew;
                float rs = 0.f;
#pragma unroll
                for (int t = 0; t < 4; ++t) {
                    bool diag = (kt0 + t * 16 + 15) > (qb0 + nq * 16);
                    unsigned pu[4];
#pragma unroll
                    for (int r = 0; r < 4; ++r) {
                        float p = EXP2F(s[t][nq][r] - mnew);
                        unsigned u = __float_as_uint(p) & 0xffff0000u;  // trunc to bf16
                        if (!allones) {
                            int amr = __shfl(amv, t * 16 + quad * 4 + r);
                            u = amr ? u : 0u;
                        }
                        if (diag) {
                            int kv = kt0 + t * 16 + quad * 4 + r;
                            u = (kv <= qv) ? u : 0u;
                        }
                        pu[r] = u;
                        rs += __uint_as_float(u);      // l consistent w/ stored P
                    }
                    pk[t][nq][0] = pack_hi16(pu[1], pu[0]);
                    pk[t][nq][1] = pack_hi16(pu[3], pu[2]);
                }
                rs += __shfl_xor(rs, 16);
                rs += __shfl_xor(rs, 32);
                ls[nq] = ls[nq] * alpha + rs;
#pragma unroll
                for (int mi = 0; mi < 4; ++mi)
#pragma unroll
                    for (int r = 0; r < 4; ++r) o[mi][nq][r] *= alpha;
            }

            // ---- O^T += V^T P^T ----
#if HAS_MFMA_1K
#pragma unroll
            for (int t = 0; t < 4; ++t) {
#pragma unroll
                for (int mi = 0; mi < 4; ++mi) {
                    int rr = mi * 16 + l16;
                    int cidx = (2 * t + (quad >> 1)) ^ (l16 & 7);
                    shortx4 vf = *(const shortx4*)(Vs + rr * 64 + cidx * 8 + (quad & 1) * 4);
#pragma unroll
                    for (int nq = 0; nq < 2; ++nq) {
                        union { unsigned u[2]; shortx4 s; } pb;
                        pb.u[0] = pk[t][nq][0]; pb.u[1] = pk[t][nq][1];
                        o[mi][nq] = __builtin_amdgcn_mfma_f32_16x16x16bf16_1k(
                            vf, pb.s, o[mi][nq], 0, 0, 0);
                    }
                }
            }
#else
            // Fallback: K=32 PV, B frags built via ds_bpermute from pk
#pragma unroll
            for (int kk2 = 0; kk2 < 2; ++kk2) {
                unsigned bfr[2][4];
#pragma unroll
                for (int nq = 0; nq < 2; ++nq)
#pragma unroll
                    for (int jj = 0; jj < 4; ++jj) {
                        int srclane = (((quad & 1) * 2 + (jj >> 1)) * 16 + l16) << 2;
                        int lo = __builtin_amdgcn_ds_bpermute(srclane, (int)pk[kk2 * 2][nq][jj & 1]);
                        int hi = __builtin_amdgcn_ds_bpermute(srclane, (int)pk[kk2 * 2 + 1][nq][jj & 1]);
                        bfr[nq][jj] = (quad >> 1) ? (unsigned)hi : (unsigned)lo;
                    }
#pragma unroll
                for (int mi = 0; mi < 4; ++mi) {
                    int rr = mi * 16 + l16;
                    int cidx = (kk2 * 4 + quad) ^ (l16 & 7);
                    shortx8 vf8 = *(const shortx8*)(Vs + rr * 64 + cidx * 8);
#pragma unroll
                    for (int nq = 0; nq < 2; ++nq) {
                        union { unsigned u[4]; shortx8 s; } pb;
#pragma unroll
                        for (int jj = 0; jj < 4; ++jj) pb.u[jj] = bfr[nq][jj];
                        o[mi][nq] = __builtin_amdgcn_mfma_f32_16x16x32_bf16(
                            vf8, pb.s, o[mi][nq], 0, 0, 0);
                    }
                }
            }
#endif
            __syncthreads();
        }

        // ---- epilogue: O^T/l -> [B,T,C] ws (d = mi*16+quad*4+r contiguous) ----
#pragma unroll
        for (int nq = 0; nq < 2; ++nq) {
            float inv = 1.0f / ls[nq];
            int q = qb0 + nq * 16 + l16;
#pragma unroll
            for (int mi = 0; mi < 4; ++mi) {
                shortx4 st;
#pragma unroll
                for (int r = 0; r < 4; ++r) st[r] = f2bf(o[mi][nq][r] * inv);
                *(shortx4*)(O + ((size_t)(b * TSEQ + q)) * CDIM + h * HDIM + mi * 16 + quad * 4) = st;
            }
        }
    }
}

// -------------------------------------------------------------------------
// GEMM2: out = attn @ Wo^T + bo. All-bf16 staging, fp32 output.
// -------------------------------------------------------------------------
__global__ __launch_bounds__(256) void gemm_out_kernel(
    const short* __restrict__ A,      // Aw [MTOT, CDIM] bf16
    const short* __restrict__ W,      // Wob [CDIM, CDIM] bf16
    const float* __restrict__ bias,   // [CDIM] fp32
    float* __restrict__ Out)          // [MTOT, CDIM] fp32
{
    __shared__ short As[128 * 32];
    __shared__ short Bs[128 * 32];
    const int tid  = threadIdx.x;
    const int lane = tid & 63, wave = tid >> 6;
    const int quad = lane >> 4, l16 = lane & 15;
    const int wr = wave >> 1, wc = wave & 1;
    const int row0 = blockIdx.x * 128;
    const int col0 = blockIdx.y * 128;
    const int K = CDIM;

    floatx4 acc[4][4] = {};

    for (int k0 = 0; k0 < K; k0 += 32) {
        stageA_bf16(A, As, row0, K, k0, tid, wave);
        stageA_bf16(W, Bs, col0, K, k0, tid, wave);
        __syncthreads();

        shortx8 af[4], bfr[4];
#pragma unroll
        for (int mi = 0; mi < 4; ++mi)
            af[mi] = *(const shortx8*)(As + (wr * 64 + mi * 16 + l16) * 32 + quad * 8);
#pragma unroll
        for (int ni = 0; ni < 4; ++ni)
            bfr[ni] = *(const shortx8*)(Bs + (wc * 64 + ni * 16 + l16) * 32 + quad * 8);
#pragma unroll
        for (int mi = 0; mi < 4; ++mi)
#pragma unroll
            for (int ni = 0; ni < 4; ++ni)
                acc[mi][ni] = __builtin_amdgcn_mfma_f32_16x16x32_bf16(
                    af[mi], bfr[ni], acc[mi][ni], 0, 0, 0);
        __syncthreads();
    }

#pragma unroll
    for (int mi = 0; mi < 4; ++mi) {
        int m = row0 + wr * 64 + mi * 16 + quad * 4;
#pragma unroll
        for (int ni = 0; ni < 4; ++ni) {
            int n = col0 + wc * 64 + ni * 16 + l16;
            float bv = bias[n];
#pragma unroll
            for (int r = 0; r < 4; ++r)
                Out[(size_t)(m + r) * CDIM + n] = acc[mi][ni][r] + bv;
        }
    }
}

// -------------------------------------------------------------------------
// ws (64 MB, proven): slot 16MB (hsb, later Aw) | Qw 16MB | Kw 16MB (later
// Wob) | VTw 16MB
// -------------------------------------------------------------------------
extern "C" void kernel_launch(void* const* d_in, const int* in_sizes, int n_in,
                              void* d_out, int out_size, void* d_ws, size_t ws_size,
                              hipStream_t stream)
{
    const float* hs   = (const float*)d_in[0];
    const int*   am   = (const int*)d_in[1];
    const float* Wqkv = (const float*)d_in[2];
    const float* bqkv = (const float*)d_in[3];
    const float* Wo   = (const float*)d_in[4];
    const float* bo   = (const float*)d_in[5];
    float* out = (float*)d_out;

    char* ws = (char*)d_ws;
    short* slot = (short*)ws;                               // hsb -> Aw
    short* Qw   = (short*)(ws + ((size_t)16 << 20));
    short* Kw   = (short*)(ws + ((size_t)32 << 20));        // K -> Wob
    short* VTw  = (short*)(ws + ((size_t)48 << 20));

    // hs fp32 -> bf16
    cvt_kernel<<<dim3((MTOT * CDIM / 4 + 255) / 256), 256, 0, stream>>>(
        (const float4*)hs, (shortx4*)slot, MTOT * CDIM / 4);
    gemm_qkv_kernel<<<dim3(MTOT / 128, (3 * CDIM) / 128), 256, 0, stream>>>(
        slot, Wqkv, bqkv, Qw, Kw, VTw);
    attn_kernel<<<dim3(8, BATCH * NH), 256, 0, stream>>>(
        Qw, Kw, VTw, am, slot);
    // Wo fp32 -> bf16 into dead K region
    cvt_kernel<<<dim3((CDIM * CDIM / 4 + 255) / 256), 256, 0, stream>>>(
        (const float4*)Wo, (shortx4*)Kw, CDIM * CDIM / 4);
    gemm_out_kernel<<<dim3(MTOT / 128, CDIM / 128), 256, 0, stream>>>(
        slot, Kw, bo, out);
}

// Round 4
// 298.194 us; speedup vs baseline: 1.7914x; 1.1325x over previous
//
#include <hip/hip_runtime.h>
#include <cstdint>
#include <cstddef>
#include <math.h>

// Problem constants (Attention_17042430230543): fp32 in / fp32 out (proven R2)
#define BATCH 4
#define TSEQ  2048
#define CDIM  1024
#define NH    16
#define HDIM  64
#define MTOT  (BATCH * TSEQ)   // 8192

typedef __attribute__((ext_vector_type(4))) float  floatx4;
typedef __attribute__((ext_vector_type(8))) short  shortx8;
typedef __attribute__((ext_vector_type(4))) short  shortx4;

__device__ __forceinline__ short f2bf(float f) {
    union { float f; unsigned int u; } v; v.f = f;
    unsigned int lsb = (v.u >> 16) & 1u;
    v.u += 0x7fffu + lsb;           // RNE
    return (short)(v.u >> 16);
}

#if defined(__has_builtin)
#  if __has_builtin(__builtin_amdgcn_exp2f)
#    define EXP2F(x) __builtin_amdgcn_exp2f(x)
#  else
#    define EXP2F(x) exp2f(x)
#  endif
#  if __has_builtin(__builtin_amdgcn_perm)
__device__ __forceinline__ unsigned pack_hi16(unsigned hi, unsigned lo) {
    return __builtin_amdgcn_perm(hi, lo, 0x07060302u);   // [lo>>16, hi>>16]
}
#  else
__device__ __forceinline__ unsigned pack_hi16(unsigned hi, unsigned lo) {
    return (lo >> 16) | (hi & 0xffff0000u);
}
#  endif
#  if __has_builtin(__builtin_amdgcn_mfma_f32_16x16x16bf16_1k)
#    define HAS_MFMA_1K 1
#  else
#    define HAS_MFMA_1K 0
#  endif
#else
#  define EXP2F(x) exp2f(x)
__device__ __forceinline__ unsigned pack_hi16(unsigned hi, unsigned lo) {
    return (lo >> 16) | (hi & 0xffff0000u);
}
#  define HAS_MFMA_1K 0
#endif

// log2(e) folded into Q so softmax exp runs on raw v_exp_f32 (exp2).
#define QSCALE (0.125f * 1.44269504088896f)

// -------------------------------------------------------------------------
// fp32 -> bf16 elementwise convert (memory-bound)
// -------------------------------------------------------------------------
__global__ __launch_bounds__(256) void cvt_kernel(const float4* __restrict__ src,
                                                  shortx4* __restrict__ dst, int n4)
{
    int i = blockIdx.x * 256 + threadIdx.x;
    if (i < n4) {
        float4 v = src[i];
        shortx4 s;
        s[0] = f2bf(v.x); s[1] = f2bf(v.y); s[2] = f2bf(v.z); s[3] = f2bf(v.w);
        dst[i] = s;
    }
}

// Fused 3-way convert: hs (8192 blocks), Wqkv (3072 blocks), Wo (1024 blocks).
// All counts are exact multiples of 256 float4s -> no bounds checks.
__global__ __launch_bounds__(256) void cvt3_kernel(
    const float4* __restrict__ s1, shortx4* __restrict__ d1,
    const float4* __restrict__ s2, shortx4* __restrict__ d2,
    const float4* __restrict__ s3, shortx4* __restrict__ d3)
{
    int bid = blockIdx.x;
    const float4* s; shortx4* d; int i;
    if (bid < 8192)       { s = s1; d = d1; i = bid * 256 + threadIdx.x; }
    else if (bid < 11264) { s = s2; d = d2; i = (bid - 8192) * 256 + threadIdx.x; }
    else                  { s = s3; d = d3; i = (bid - 11264) * 256 + threadIdx.x; }
    float4 v = s[i];
    shortx4 o;
    o[0] = f2bf(v.x); o[1] = f2bf(v.y); o[2] = f2bf(v.z); o[3] = f2bf(v.w);
    d[i] = o;
}

// Stage 128x32 bf16 tile via async global_load_lds (width 16).
__device__ __forceinline__ void stageA_bf16(const short* g, short* S, int row0,
                                            int K, int k0, int tid, int wave)
{
#pragma unroll
    for (int i = 0; i < 2; ++i) {
        int c = i * 256 + tid;            // 16B chunk index
        int r = c >> 2, kc = c & 3;
        __builtin_amdgcn_global_load_lds(
            (__attribute__((address_space(1))) void*)(g + (size_t)(row0 + r) * K + k0 + kc * 8),
            (__attribute__((address_space(3))) void*)((char*)S + i * 4096 + wave * 1024),
            16, 0, 0);
    }
}
// Stage 128x32 from fp32 source, converting to bf16 (slow-path only).
__device__ __forceinline__ void stageB_f32(const float* g, short* S, int row0,
                                           int K, int k0, int tid)
{
#pragma unroll
    for (int i = 0; i < 4; ++i) {
        int c = i * 256 + tid;            // 4-float chunk index
        int r = c >> 3, fc = c & 7;
        const float4 v = *(const float4*)(g + (size_t)(row0 + r) * K + k0 + fc * 4);
        shortx4 s4;
        s4[0] = f2bf(v.x); s4[1] = f2bf(v.y); s4[2] = f2bf(v.z); s4[3] = f2bf(v.w);
        *(shortx4*)(S + r * 32 + fc * 4) = s4;
    }
}

// -------------------------------------------------------------------------
// GEMM1 epilogue (shared): scatter acc -> Q [B,H,T,D] (scaled), K [B,H,T,D],
// V^T [B,H,D,T].
// -------------------------------------------------------------------------
__device__ __forceinline__ void qkv_epilogue(
    floatx4 (&acc)[4][4], const float* bias,
    short* Qo, short* Ko, short* VTo,
    int row0, int col0, int wr, int wc, int quad, int l16)
{
#pragma unroll
    for (int mi = 0; mi < 4; ++mi) {
        int m = row0 + wr * 64 + mi * 16 + quad * 4;
        int b = m >> 11, t0 = m & (TSEQ - 1);
#pragma unroll
        for (int ni = 0; ni < 4; ++ni) {
            int n = col0 + wc * 64 + ni * 16 + l16;
            float bv = bias[n];
            int part = n >> 10, rem = n & 1023;
            int h = rem >> 6, d = rem & 63;
            if (part == 2) {
                shortx4 st;
#pragma unroll
                for (int r = 0; r < 4; ++r) st[r] = f2bf(acc[mi][ni][r] + bv);
                *(shortx4*)(VTo + (((size_t)(b * NH + h)) * HDIM + d) * TSEQ + t0) = st;
            } else {
                short* dst = (part == 0) ? Qo : Ko;
                float scale = (part == 0) ? QSCALE : 1.0f;
#pragma unroll
                for (int r = 0; r < 4; ++r) {
                    size_t idx = (((size_t)(b * NH + h)) * TSEQ + (t0 + r)) * HDIM + d;
                    dst[idx] = f2bf((acc[mi][ni][r] + bv) * scale);
                }
            }
        }
    }
}

// Fast path: both operands bf16, m97 staging.
__global__ __launch_bounds__(256) void gemm_qkv_fast_kernel(
    const short* __restrict__ A,      // hsb [MTOT, CDIM] bf16
    const short* __restrict__ W,      // Wqkvb [3C, C] bf16
    const float* __restrict__ bias,   // [3C] fp32
    short* __restrict__ Qo, short* __restrict__ Ko, short* __restrict__ VTo)
{
    __shared__ short As[128 * 32];
    __shared__ short Bs[128 * 32];
    const int tid  = threadIdx.x;
    const int lane = tid & 63, wave = tid >> 6;
    const int quad = lane >> 4, l16 = lane & 15;
    const int wr = wave >> 1, wc = wave & 1;
    const int row0 = blockIdx.x * 128;
    const int col0 = blockIdx.y * 128;
    const int K = CDIM;

    floatx4 acc[4][4] = {};

    for (int k0 = 0; k0 < K; k0 += 32) {
        stageA_bf16(A, As, row0, K, k0, tid, wave);
        stageA_bf16(W, Bs, col0, K, k0, tid, wave);
        __syncthreads();

        shortx8 af[4], bfr[4];
#pragma unroll
        for (int mi = 0; mi < 4; ++mi)
            af[mi] = *(const shortx8*)(As + (wr * 64 + mi * 16 + l16) * 32 + quad * 8);
#pragma unroll
        for (int ni = 0; ni < 4; ++ni)
            bfr[ni] = *(const shortx8*)(Bs + (wc * 64 + ni * 16 + l16) * 32 + quad * 8);
#pragma unroll
        for (int mi = 0; mi < 4; ++mi)
#pragma unroll
            for (int ni = 0; ni < 4; ++ni)
                acc[mi][ni] = __builtin_amdgcn_mfma_f32_16x16x32_bf16(
                    af[mi], bfr[ni], acc[mi][ni], 0, 0, 0);
        __syncthreads();
    }
    qkv_epilogue(acc, bias, Qo, Ko, VTo, row0, col0, wr, wc, quad, l16);
}

// Slow path (ws too small): B staged from fp32 (R3 behavior).
__global__ __launch_bounds__(256) void gemm_qkv_kernel(
    const short* __restrict__ A,      // hsb [MTOT, CDIM] bf16
    const float* __restrict__ W,      // [3C, C] fp32
    const float* __restrict__ bias,   // [3C] fp32
    short* __restrict__ Qo, short* __restrict__ Ko, short* __restrict__ VTo)
{
    __shared__ short As[128 * 32];
    __shared__ short Bs[128 * 32];
    const int tid  = threadIdx.x;
    const int lane = tid & 63, wave = tid >> 6;
    const int quad = lane >> 4, l16 = lane & 15;
    const int wr = wave >> 1, wc = wave & 1;
    const int row0 = blockIdx.x * 128;
    const int col0 = blockIdx.y * 128;
    const int K = CDIM;

    floatx4 acc[4][4] = {};

    for (int k0 = 0; k0 < K; k0 += 32) {
        stageA_bf16(A, As, row0, K, k0, tid, wave);
        stageB_f32(W, Bs, col0, K, k0, tid);
        __syncthreads();

        shortx8 af[4], bfr[4];
#pragma unroll
        for (int mi = 0; mi < 4; ++mi)
            af[mi] = *(const shortx8*)(As + (wr * 64 + mi * 16 + l16) * 32 + quad * 8);
#pragma unroll
        for (int ni = 0; ni < 4; ++ni)
            bfr[ni] = *(const shortx8*)(Bs + (wc * 64 + ni * 16 + l16) * 32 + quad * 8);
#pragma unroll
        for (int mi = 0; mi < 4; ++mi)
#pragma unroll
            for (int ni = 0; ni < 4; ++ni)
                acc[mi][ni] = __builtin_amdgcn_mfma_f32_16x16x32_bf16(
                    af[mi], bfr[ni], acc[mi][ni], 0, 0, 0);
        __syncthreads();
    }
    qkv_epilogue(acc, bias, Qo, Ko, VTo, row0, col0, wr, wc, quad, l16);
}

// -------------------------------------------------------------------------
// Flash attention, S^T formulation (unchanged from R3 — counters next round).
// -------------------------------------------------------------------------
__global__ __launch_bounds__(256) void attn_kernel(
    const short* __restrict__ Q,    // [B*H, T, D] bf16, pre-scaled
    const short* __restrict__ Kg,   // [B*H, T, D] bf16
    const short* __restrict__ VT,   // [B*H, D, T] bf16
    const int*   __restrict__ am,   // [B, T]
    short* __restrict__ O)          // [B, T, C] bf16
{
    __shared__ short Ks[64 * 64];   // swizzled [kv][d]
    __shared__ short Vs[64 * 64];   // swizzled [d][kv]

    const int tid  = threadIdx.x;
    const int lane = tid & 63, wave = tid >> 6;
    const int quad = lane >> 4, l16 = lane & 15;
    const int bh = blockIdx.y, b = bh >> 4, h = bh & 15;

    const short* Qb = Q  + (size_t)bh * TSEQ * HDIM;
    const short* Kb = Kg + (size_t)bh * TSEQ * HDIM;
    const short* Vb = VT + (size_t)bh * HDIM * TSEQ;

    for (int pass = 0; pass < 2; ++pass) {
        const int strip = pass ? (15 - blockIdx.x) : blockIdx.x;
        const int q0  = strip * 128;
        const int qb0 = q0 + wave * 32;
        const int qv0 = qb0 + l16;
        const int qv1 = qv0 + 16;

        shortx8 bq[2][2];
#pragma unroll
        for (int nq = 0; nq < 2; ++nq)
#pragma unroll
            for (int kk = 0; kk < 2; ++kk)
                bq[nq][kk] = *(const shortx8*)(
                    Qb + (size_t)(qb0 + nq * 16 + l16) * HDIM + kk * 32 + quad * 8);

        floatx4 o[4][2] = {};
        float ms[2] = { -INFINITY, -INFINITY };
        float ls[2] = { 0.f, 0.f };

        const int ntiles = (q0 + 128) >> 6;
        for (int kt = 0; kt < ntiles; ++kt) {
            const int kt0 = kt << 6;
#pragma unroll
            for (int i = 0; i < 2; ++i) {
                int idx = i * 256 + tid;
                int rr = idx >> 3, cd = idx & 7;
                int c = cd ^ (rr & 7);
                __builtin_amdgcn_global_load_lds(
                    (__attribute__((address_space(1))) void*)(Kb + (size_t)(kt0 + rr) * HDIM + c * 8),
                    (__attribute__((address_space(3))) void*)((char*)Ks + i * 4096 + wave * 1024),
                    16, 0, 0);
                __builtin_amdgcn_global_load_lds(
                    (__attribute__((address_space(1))) void*)(Vb + (size_t)rr * TSEQ + kt0 + c * 8),
                    (__attribute__((address_space(3))) void*)((char*)Vs + i * 4096 + wave * 1024),
                    16, 0, 0);
            }
            int amv = am[b * TSEQ + kt0 + lane];
            bool allones = (__ballot(amv != 0) == 0xFFFFFFFFFFFFFFFFULL);
            __syncthreads();

            floatx4 s[4][2] = {};
#pragma unroll
            for (int kk = 0; kk < 2; ++kk)
#pragma unroll
                for (int t = 0; t < 4; ++t) {
                    int rr = t * 16 + l16;
                    shortx8 kf = *(const shortx8*)(
                        Ks + rr * 64 + (((kk * 4 + quad) ^ (l16 & 7)) << 3));
#pragma unroll
                    for (int nq = 0; nq < 2; ++nq)
                        s[t][nq] = __builtin_amdgcn_mfma_f32_16x16x32_bf16(
                            kf, bq[nq][kk], s[t][nq], 0, 0, 0);
                }

            unsigned pk[4][2][2];
#pragma unroll
            for (int nq = 0; nq < 2; ++nq) {
                const int qv = nq ? qv1 : qv0;
                float mx = s[0][nq][0];
#pragma unroll
                for (int t = 0; t < 4; ++t)
#pragma unroll
                    for (int r = 0; r < 4; ++r) mx = fmaxf(mx, s[t][nq][r]);
                mx = fmaxf(mx, __shfl_xor(mx, 16));
                mx = fmaxf(mx, __shfl_xor(mx, 32));
                float mnew  = fmaxf(ms[nq], mx);
                float alpha = EXP2F(ms[nq] - mnew);
                ms[nq] = mnew;
                float rs = 0.f;
#pragma unroll
                for (int t = 0; t < 4; ++t) {
                    bool diag = (kt0 + t * 16 + 15) > (qb0 + nq * 16);
                    unsigned pu[4];
#pragma unroll
                    for (int r = 0; r < 4; ++r) {
                        float p = EXP2F(s[t][nq][r] - mnew);
                        unsigned u = __float_as_uint(p) & 0xffff0000u;
                        if (!allones) {
                            int amr = __shfl(amv, t * 16 + quad * 4 + r);
                            u = amr ? u : 0u;
                        }
                        if (diag) {
                            int kv = kt0 + t * 16 + quad * 4 + r;
                            u = (kv <= qv) ? u : 0u;
                        }
                        pu[r] = u;
                        rs += __uint_as_float(u);
                    }
                    pk[t][nq][0] = pack_hi16(pu[1], pu[0]);
                    pk[t][nq][1] = pack_hi16(pu[3], pu[2]);
                }
                rs += __shfl_xor(rs, 16);
                rs += __shfl_xor(rs, 32);
                ls[nq] = ls[nq] * alpha + rs;
#pragma unroll
                for (int mi = 0; mi < 4; ++mi)
#pragma unroll
                    for (int r = 0; r < 4; ++r) o[mi][nq][r] *= alpha;
            }

#if HAS_MFMA_1K
#pragma unroll
            for (int t = 0; t < 4; ++t) {
#pragma unroll
                for (int mi = 0; mi < 4; ++mi) {
                    int rr = mi * 16 + l16;
                    int cidx = (2 * t + (quad >> 1)) ^ (l16 & 7);
                    shortx4 vf = *(const shortx4*)(Vs + rr * 64 + cidx * 8 + (quad & 1) * 4);
#pragma unroll
                    for (int nq = 0; nq < 2; ++nq) {
                        union { unsigned u[2]; shortx4 s; } pb;
                        pb.u[0] = pk[t][nq][0]; pb.u[1] = pk[t][nq][1];
                        o[mi][nq] = __builtin_amdgcn_mfma_f32_16x16x16bf16_1k(
                            vf, pb.s, o[mi][nq], 0, 0, 0);
                    }
                }
            }
#else
#pragma unroll
            for (int kk2 = 0; kk2 < 2; ++kk2) {
                unsigned bfr[2][4];
#pragma unroll
                for (int nq = 0; nq < 2; ++nq)
#pragma unroll
                    for (int jj = 0; jj < 4; ++jj) {
                        int srclane = (((quad & 1) * 2 + (jj >> 1)) * 16 + l16) << 2;
                        int lo = __builtin_amdgcn_ds_bpermute(srclane, (int)pk[kk2 * 2][nq][jj & 1]);
                        int hi = __builtin_amdgcn_ds_bpermute(srclane, (int)pk[kk2 * 2 + 1][nq][jj & 1]);
                        bfr[nq][jj] = (quad >> 1) ? (unsigned)hi : (unsigned)lo;
                    }
#pragma unroll
                for (int mi = 0; mi < 4; ++mi) {
                    int rr = mi * 16 + l16;
                    int cidx = (kk2 * 4 + quad) ^ (l16 & 7);
                    shortx8 vf8 = *(const shortx8*)(Vs + rr * 64 + cidx * 8);
#pragma unroll
                    for (int nq = 0; nq < 2; ++nq) {
                        union { unsigned u[4]; shortx8 s; } pb;
#pragma unroll
                        for (int jj = 0; jj < 4; ++jj) pb.u[jj] = bfr[nq][jj];
                        o[mi][nq] = __builtin_amdgcn_mfma_f32_16x16x32_bf16(
                            vf8, pb.s, o[mi][nq], 0, 0, 0);
                    }
                }
            }
#endif
            __syncthreads();
        }

#pragma unroll
        for (int nq = 0; nq < 2; ++nq) {
            float inv = 1.0f / ls[nq];
            int q = qb0 + nq * 16 + l16;
#pragma unroll
            for (int mi = 0; mi < 4; ++mi) {
                shortx4 st;
#pragma unroll
                for (int r = 0; r < 4; ++r) st[r] = f2bf(o[mi][nq][r] * inv);
                *(shortx4*)(O + ((size_t)(b * TSEQ + q)) * CDIM + h * HDIM + mi * 16 + quad * 4) = st;
            }
        }
    }
}

// -------------------------------------------------------------------------
// GEMM2: out = attn @ Wo^T + bo. All-bf16 staging, fp32 output.
// -------------------------------------------------------------------------
__global__ __launch_bounds__(256) void gemm_out_kernel(
    const short* __restrict__ A,      // Aw [MTOT, CDIM] bf16
    const short* __restrict__ W,      // Wob [CDIM, CDIM] bf16
    const float* __restrict__ bias,   // [CDIM] fp32
    float* __restrict__ Out)          // [MTOT, CDIM] fp32
{
    __shared__ short As[128 * 32];
    __shared__ short Bs[128 * 32];
    const int tid  = threadIdx.x;
    const int lane = tid & 63, wave = tid >> 6;
    const int quad = lane >> 4, l16 = lane & 15;
    const int wr = wave >> 1, wc = wave & 1;
    const int row0 = blockIdx.x * 128;
    const int col0 = blockIdx.y * 128;
    const int K = CDIM;

    floatx4 acc[4][4] = {};

    for (int k0 = 0; k0 < K; k0 += 32) {
        stageA_bf16(A, As, row0, K, k0, tid, wave);
        stageA_bf16(W, Bs, col0, K, k0, tid, wave);
        __syncthreads();

        shortx8 af[4], bfr[4];
#pragma unroll
        for (int mi = 0; mi < 4; ++mi)
            af[mi] = *(const shortx8*)(As + (wr * 64 + mi * 16 + l16) * 32 + quad * 8);
#pragma unroll
        for (int ni = 0; ni < 4; ++ni)
            bfr[ni] = *(const shortx8*)(Bs + (wc * 64 + ni * 16 + l16) * 32 + quad * 8);
#pragma unroll
        for (int mi = 0; mi < 4; ++mi)
#pragma unroll
            for (int ni = 0; ni < 4; ++ni)
                acc[mi][ni] = __builtin_amdgcn_mfma_f32_16x16x32_bf16(
                    af[mi], bfr[ni], acc[mi][ni], 0, 0, 0);
        __syncthreads();
    }

#pragma unroll
    for (int mi = 0; mi < 4; ++mi) {
        int m = row0 + wr * 64 + mi * 16 + quad * 4;
#pragma unroll
        for (int ni = 0; ni < 4; ++ni) {
            int n = col0 + wc * 64 + ni * 16 + l16;
            float bv = bias[n];
#pragma unroll
            for (int r = 0; r < 4; ++r)
                Out[(size_t)(m + r) * CDIM + n] = acc[mi][ni][r] + bv;
        }
    }
}

// -------------------------------------------------------------------------
// Fast ws layout (72 MB): hsb/Aw 16 | Qw 16 | Kw 16 | VTw 16 | Wqkvb 6 | Wob 2
// Slow ws layout (64 MB): hsb/Aw 16 | Qw 16 | Kw 16 (->Wob) | VTw 16
// -------------------------------------------------------------------------
extern "C" void kernel_launch(void* const* d_in, const int* in_sizes, int n_in,
                              void* d_out, int out_size, void* d_ws, size_t ws_size,
                              hipStream_t stream)
{
    const float* hs   = (const float*)d_in[0];
    const int*   am   = (const int*)d_in[1];
    const float* Wqkv = (const float*)d_in[2];
    const float* bqkv = (const float*)d_in[3];
    const float* Wo   = (const float*)d_in[4];
    const float* bo   = (const float*)d_in[5];
    float* out = (float*)d_out;

    char* ws = (char*)d_ws;
    short* slot = (short*)ws;                               // hsb -> Aw
    short* Qw   = (short*)(ws + ((size_t)16 << 20));
    short* Kw   = (short*)(ws + ((size_t)32 << 20));
    short* VTw  = (short*)(ws + ((size_t)48 << 20));

    if (ws_size >= ((size_t)72 << 20)) {
        short* Wqkvb = (short*)(ws + ((size_t)64 << 20));
        short* Wob   = (short*)(ws + ((size_t)70 << 20));
        cvt3_kernel<<<dim3(12288), 256, 0, stream>>>(
            (const float4*)hs,   (shortx4*)slot,
            (const float4*)Wqkv, (shortx4*)Wqkvb,
            (const float4*)Wo,   (shortx4*)Wob);
        gemm_qkv_fast_kernel<<<dim3(MTOT / 128, (3 * CDIM) / 128), 256, 0, stream>>>(
            slot, Wqkvb, bqkv, Qw, Kw, VTw);
        attn_kernel<<<dim3(8, BATCH * NH), 256, 0, stream>>>(
            Qw, Kw, VTw, am, slot);
        gemm_out_kernel<<<dim3(MTOT / 128, CDIM / 128), 256, 0, stream>>>(
            slot, Wob, bo, out);
    } else {
        cvt_kernel<<<dim3((MTOT * CDIM / 4 + 255) / 256), 256, 0, stream>>>(
            (const float4*)hs, (shortx4*)slot, MTOT * CDIM / 4);
        gemm_qkv_kernel<<<dim3(MTOT / 128, (3 * CDIM) / 128), 256, 0, stream>>>(
            slot, Wqkv, bqkv, Qw, Kw, VTw);
        attn_kernel<<<dim3(8, BATCH * NH), 256, 0, stream>>>(
            Qw, Kw, VTw, am, slot);
        cvt_kernel<<<dim3((CDIM * CDIM / 4 + 255) / 256), 256, 0, stream>>>(
            (const float4*)Wo, (shortx4*)Kw, CDIM * CDIM / 4);
        gemm_out_kernel<<<dim3(MTOT / 128, CDIM / 128), 256, 0, stream>>>(
            slot, Kw, bo, out);
    }
}